// Round 4
// baseline (554.687 us; speedup 1.0000x reference)
//
#include <hip/hip_runtime.h>
#include <hip/hip_bf16.h>
#include <cstdint>
#include <cstddef>

// Problem: B=2, S=2048, H=16, D=64, d_model=1024
// out = proj( softmax(QK^T*scale + mask) @ V ) @ W^T + b
//
// bf16 MFMA everywhere (no fp32 MFMA on CDNA4), fp32 accumulation.
// Memory floor = 268MB fp32 mask read. Attention blocks process BOTH batches
// (mask shared across batch) so mask is fetched from HBM exactly once.
// attn: 8 waves/block (16 q-rows each).
//  (a) head-affine XCD swizzle: XCD c owns heads {2c,2c+1} so K/V live in ONE
//      per-XCD L2 instead of being re-fetched into all 8.
//  (b) 2-deep mask register pipeline: body(t) consumes mcur and, after its
//      last read (b==1 scores), prefetches tile t+2 into mcur. (R3 FIX:
//      R2 wrongly prefetched into mnext, clobbering tile t+1's mask.)

#define B_ 2
#define S_ 2048
#define H_ 16
#define D_ 64
#define DM 1024
#define QBLK 128
#define KBLK 64
#define NT (S_ / KBLK)   // 32 k-tiles

typedef __attribute__((ext_vector_type(8))) short short8_t;
typedef __attribute__((ext_vector_type(4))) float float4_t;

#define MFMA(a, b, c) __builtin_amdgcn_mfma_f32_16x16x32_bf16((a), (b), (c), 0, 0, 0)

#if defined(__has_builtin) && __has_builtin(__builtin_amdgcn_exp2f)
static __device__ __forceinline__ float exp2_fast(float x) {
  return __builtin_amdgcn_exp2f(x);
}
#else
static __device__ __forceinline__ float exp2_fast(float x) {
  float r;
  asm volatile("v_exp_f32 %0, %1" : "=v"(r) : "v"(x));
  return r;
}
#endif

static __device__ __forceinline__ unsigned short f2bf(float f) {
  union { float f; unsigned u; } x; x.f = f;
  unsigned r = x.u + 0x7FFFu + ((x.u >> 16) & 1u);   // RNE (inputs finite)
  return (unsigned short)(r >> 16);
}

static __device__ __forceinline__ void gload16(const unsigned short* g, unsigned short* l) {
  __builtin_amdgcn_global_load_lds(
      (const __attribute__((address_space(1))) unsigned int*)g,
      (__attribute__((address_space(3))) unsigned int*)l, 16, 0, 0);
}

// ---------------------------------------------------------------------------
// prep: K -> bf16 (same layout), V -> bf16 transposed [b][h][d][S]
// so both are stageable by global_load_lds (contiguous along the needed axis).
// ---------------------------------------------------------------------------
__global__ __launch_bounds__(256)
void prep_kernel(const float* __restrict__ kin, const float* __restrict__ vin,
                 unsigned short* __restrict__ kbf, unsigned short* __restrict__ vtr) {
  const int bid = blockIdx.x;
  if (bid < 2048) {
    // K cast: 4M elements, 8 per thread, coalesced 16B stores
    const size_t base = (size_t)bid * 2048 + (size_t)threadIdx.x * 8;
    float4_t f0 = *(const float4_t*)(kin + base);
    float4_t f1 = *(const float4_t*)(kin + base + 4);
    short8_t v;
#pragma unroll
    for (int j = 0; j < 4; ++j) { v[j] = (short)f2bf(f0[j]); v[4 + j] = (short)f2bf(f1[j]); }
    *(short8_t*)(kbf + base) = v;
  } else {
    // V transpose per (b,h,s-tile of 64): LDS 64x64 tile transpose
    const int id = bid - 2048;              // 0..1023
    const int b = id >> 9, h = (id >> 5) & 15, st = id & 31;
    __shared__ unsigned short tile[64][66]; // +2 pad
    {
      const int s = threadIdx.x >> 2, dq = threadIdx.x & 3;
      const float* src = vin + (((size_t)(b * S_ + st * 64 + s) * H_ + h) << 6) + dq * 16;
#pragma unroll
      for (int i = 0; i < 4; ++i) {
        float4_t f = *(const float4_t*)(src + i * 4);
#pragma unroll
        for (int j = 0; j < 4; ++j) tile[s][dq * 16 + i * 4 + j] = f2bf(f[j]);
      }
    }
    __syncthreads();
    {
      const int d = threadIdx.x >> 2, sq = threadIdx.x & 3;
      alignas(16) unsigned short o[16];
#pragma unroll
      for (int j = 0; j < 16; ++j) o[j] = tile[sq * 16 + j][d];
      unsigned short* dst = vtr + (((size_t)((b * H_ + h) * D_ + d)) << 11) + st * 64 + sq * 16;
      *(short8_t*)dst = *(const short8_t*)&o[0];
      *(short8_t*)(dst + 8) = *(const short8_t*)&o[8];
    }
  }
}

// ---------------------------------------------------------------------------
// Flash attention. Grid 256 blocks, 512 threads = 8 waves, each wave owns 16
// q-rows; block handles BOTH batches (mask read once from HBM).
// Block->(qtile,head) mapping is head-affine to XCDs: lin%8 = XCD owns heads
// {2*(lin%8), 2*(lin%8)+1} so each head's K/V stays in one per-XCD L2.
// K_lds rows permuted p(k) = (k>>2) + 16*(k&3) so score-fragment c reads
// physical rows p = n + 16c, giving score(hw col n, frag c) = key 4n+c ->
// mask becomes a per-lane float4 load. All LDS tiles XOR-chunk-swizzled
// (chunk_phys = chunk_logical ^ (row&7)), applied identically on the
// global_load_lds SOURCE side and the ds_read side (rule: both-or-neither).
// kappa(l,j) = (l>>4)*8+j is used on BOTH mfma operands everywhere, so any
// hardware K-slot permutation cancels.
// ---------------------------------------------------------------------------
__global__ __launch_bounds__(512, 2)
void attn_kernel(const float* __restrict__ qin,
                 const float* __restrict__ mask,
                 const unsigned short* __restrict__ kbf,
                 const unsigned short* __restrict__ vtr,
                 unsigned short* __restrict__ ctx) {
  __shared__ unsigned short k_lds[2][B_][KBLK * D_];  // [buf][b][p*64+d] swizzled
  __shared__ unsigned short v_lds[2][B_][D_ * KBLK];  // [buf][b][d*64+k] swizzled
  __shared__ unsigned short p_lds[8][16 * KBLK];      // per-wave, swizzled

  const int tid = threadIdx.x;
  const int w = tid >> 6, l = tid & 63;
  const int n = l & 15, g = l >> 4;

  // head-affine XCD swizzle (bijective on 0..255):
  //   lin&7 = XCD slot c; head = 2c + ((lin>>3)&1); qtile = lin>>4
  const int lin = blockIdx.y * 16 + blockIdx.x;
  const int h = 2 * (lin & 7) + ((lin >> 3) & 1);
  const int qt = lin >> 4;
  const int qw = qt * QBLK + w * 16;

  // ---- Q fragments (A-layout: row = l&15, k-slot = g*8+j over d) ----
  short8_t qf[B_][2];
#pragma unroll
  for (int b = 0; b < B_; ++b) {
    const int row = qw + n;
#pragma unroll
    for (int ks = 0; ks < 2; ++ks) {
      const float* src = qin + (((size_t)(b * S_ + row) * H_ + h) << 6) + ks * 32 + g * 8;
      float4_t f0 = *(const float4_t*)src;
      float4_t f1 = *(const float4_t*)(src + 4);
      short8_t v;
#pragma unroll
      for (int j = 0; j < 4; ++j) { v[j] = (short)f2bf(f0[j]); v[4 + j] = (short)f2bf(f1[j]); }
      qf[b][ks] = v;
    }
  }

  float4_t oacc[B_][4];
  float m2v[B_][4], lv[B_][4];
#pragma unroll
  for (int b = 0; b < B_; ++b) {
#pragma unroll
    for (int df = 0; df < 4; ++df) oacc[b][df] = (float4_t){0.f, 0.f, 0.f, 0.f};
#pragma unroll
    for (int r = 0; r < 4; ++r) { m2v[b][r] = -1e30f; lv[b][r] = 0.f; }
  }

  // mask double-buffer registers (named, never runtime-indexed -> stay VGPR)
  float4_t mrgA[4], mrgB[4];
  auto load_mask = [&](int t, float4_t (&m)[4]) {
    const int kb = t * KBLK;
#pragma unroll
    for (int r = 0; r < 4; ++r) {
      const int row = qw + 4 * g + r;
      m[r] = *(const float4_t*)(mask + (size_t)(h * S_ + row) * S_ + kb + 4 * n);
    }
  };

  // stage K/V tiles for tile t into buf via global_load_lds (pre-swizzled src)
  auto stage = [&](int t, int buf) {
    const int kb = t * KBLK;
    const int cid = w * 64 + l;          // 16B-chunk id, 0..511
#pragma unroll
    for (int b = 0; b < B_; ++b) {
      {
        const int p = cid >> 3;
        const int c8l = (cid & 7) ^ (p & 7);
        const int krow = ((p & 15) << 2) + (p >> 4);  // inverse row permutation
        const unsigned short* src =
            kbf + (((size_t)(b * S_ + kb + krow) * H_ + h) << 6) + c8l * 8;
        gload16(src, &k_lds[buf][b][w * 512]);
      }
      {
        const int d = cid >> 3;
        const int c8l = (cid & 7) ^ (d & 7);
        const unsigned short* src =
            vtr + (((size_t)((b * H_ + h) * D_ + d)) << 11) + kb + c8l * 8;
        gload16(src, &v_lds[buf][b][w * 512]);
      }
    }
  };

  // one k-tile: compute with mcur; after mcur's last read (b==1 scores),
  // prefetch mask tile t+2 into mcur (correct 2-deep rotation: A,B,A,B,...).
  auto tile_body = [&](int t, int buf, float4_t (&mcur)[4]) {
    if (t + 1 < NT) stage(t + 1, buf ^ 1);

#pragma unroll
    for (int b = 0; b < B_; ++b) {
      // K B-fragments: frag c reads physical rows p = n + 16c
      short8_t kf[4][2];
#pragma unroll
      for (int c = 0; c < 4; ++c) {
        const int p = n + 16 * c;
#pragma unroll
        for (int ks = 0; ks < 2; ++ks)
          kf[c][ks] = *(const short8_t*)
              &k_lds[buf][b][(p * 64 + ks * 32 + g * 8) ^ ((p & 7) << 3)];
      }
      // S = QK^T, then *scale + mask, in log2 domain
      float s2[4][4];
#pragma unroll
      for (int c = 0; c < 4; ++c) {
        float4_t a = {0.f, 0.f, 0.f, 0.f};
        a = MFMA(qf[b][0], kf[c][0], a);
        a = MFMA(qf[b][1], kf[c][1], a);
#pragma unroll
        for (int r = 0; r < 4; ++r)
          s2[c][r] = a[r] * (0.125f * 1.44269504f) + mcur[r][c] * 1.44269504f;
      }

      // 2-deep prefetch into the buffer just consumed (last read was above)
      if (b == 1 && t + 2 < NT) load_mask(t + 2, mcur);

      {
        float mx[4], al[4], sm[4];
#pragma unroll
        for (int r = 0; r < 4; ++r)
          mx[r] = fmaxf(fmaxf(s2[0][r], s2[1][r]), fmaxf(s2[2][r], s2[3][r]));
#pragma unroll
        for (int r = 0; r < 4; ++r) {
          mx[r] = fmaxf(mx[r], __shfl_xor(mx[r], 1));
          mx[r] = fmaxf(mx[r], __shfl_xor(mx[r], 2));
          mx[r] = fmaxf(mx[r], __shfl_xor(mx[r], 4));
          mx[r] = fmaxf(mx[r], __shfl_xor(mx[r], 8));
        }
#pragma unroll
        for (int r = 0; r < 4; ++r) {
          const float mo = m2v[b][r];
          const float mn = fmaxf(mo, mx[r]);
          al[r] = exp2_fast(mo - mn);
          m2v[b][r] = mn;
        }
#pragma unroll
        for (int c = 0; c < 4; ++c)
#pragma unroll
          for (int r = 0; r < 4; ++r)
            s2[c][r] = exp2_fast(s2[c][r] - m2v[b][r]);
#pragma unroll
        for (int r = 0; r < 4; ++r) {
          sm[r] = (s2[0][r] + s2[1][r]) + (s2[2][r] + s2[3][r]);
          sm[r] += __shfl_xor(sm[r], 1);
          sm[r] += __shfl_xor(sm[r], 2);
          sm[r] += __shfl_xor(sm[r], 4);
          sm[r] += __shfl_xor(sm[r], 8);
          lv[b][r] = lv[b][r] * al[r] + sm[r];
        }
#pragma unroll
        for (int df = 0; df < 4; ++df)
#pragma unroll
          for (int r = 0; r < 4; ++r) oacc[b][df][r] *= al[r];
        // P -> per-wave LDS (bf16); logical col of frag c at hw col n is 4n+c
#pragma unroll
        for (int r = 0; r < 4; ++r) {
          const int row = 4 * g + r;
          unsigned u0 = (unsigned)f2bf(s2[0][r]) | ((unsigned)f2bf(s2[1][r]) << 16);
          unsigned u1 = (unsigned)f2bf(s2[2][r]) | ((unsigned)f2bf(s2[3][r]) << 16);
          uint2 uu = make_uint2(u0, u1);
          *(uint2*)&p_lds[w][(row * 64 + 4 * n) ^ ((row & 7) << 3)] = uu;
        }
      }

      // PV: A = P (from LDS, linear in logical key), B = V_t rows d = 16*df+n
      short8_t pf[2], vf[2][4];
#pragma unroll
      for (int ks = 0; ks < 2; ++ks)
        pf[ks] = *(const short8_t*)
            &p_lds[w][(n * 64 + ks * 32 + g * 8) ^ ((n & 7) << 3)];
#pragma unroll
      for (int ks = 0; ks < 2; ++ks)
#pragma unroll
        for (int df = 0; df < 4; ++df) {
          const int d = 16 * df + n;
          vf[ks][df] = *(const short8_t*)
              &v_lds[buf][b][(d * 64 + ks * 32 + g * 8) ^ ((n & 7) << 3)];
        }
#pragma unroll
      for (int df = 0; df < 4; ++df) {
        float4_t o = oacc[b][df];
        o = MFMA(pf[0], vf[0][df], o);
        o = MFMA(pf[1], vf[1][df], o);
        oacc[b][df] = o;
      }
    }
    __syncthreads();
  };

  stage(0, 0);
  load_mask(0, mrgA);
  load_mask(1, mrgB);
  __syncthreads();

  for (int t = 0; t < NT; t += 2) {
    tile_body(t, 0, mrgA);      // consumes tile t,   refills mrgA with t+2
    tile_body(t + 1, 1, mrgB);  // consumes tile t+1, refills mrgB with t+3
  }

  // epilogue: normalize, write ctx as bf16 [B*S][1024]
#pragma unroll
  for (int b = 0; b < B_; ++b) {
    float inv[4];
#pragma unroll
    for (int r = 0; r < 4; ++r) inv[r] = 1.0f / lv[b][r];
#pragma unroll
    for (int df = 0; df < 4; ++df) {
      const int d = 16 * df + n;
#pragma unroll
      for (int r = 0; r < 4; ++r) {
        const int row = qw + 4 * g + r;
        ctx[(size_t)(b * S_ + row) * DM + h * D_ + d] = f2bf(oacc[b][df][r] * inv[r]);
      }
    }
  }
}

// ---------------------------------------------------------------------------
// Projection: Y[4096][1024] = ctx(bf16) @ W^T + b.  Block 128x64, 4 waves
// (each 32x64). ctx/W are L2/L3-resident -> direct global->fragment loads.
// ---------------------------------------------------------------------------
__global__ __launch_bounds__(256, 2)
void proj_kernel(const unsigned short* __restrict__ ctx,
                 const float* __restrict__ wo,
                 const float* __restrict__ bo,
                 float* __restrict__ out) {
  const int tid = threadIdx.x;
  const int w = tid >> 6, l = tid & 63, n = l & 15, g = l >> 4;
  const int mb = blockIdx.x * 128 + w * 32;
  const int nb = blockIdx.y * 64;

  float4_t acc[2][4];
#pragma unroll
  for (int m = 0; m < 2; ++m)
#pragma unroll
    for (int nf = 0; nf < 4; ++nf) acc[m][nf] = (float4_t){0.f, 0.f, 0.f, 0.f};

#pragma unroll 2
  for (int kk = 0; kk < DM; kk += 32) {
    short8_t af[2];
#pragma unroll
    for (int m = 0; m < 2; ++m)
      af[m] = *(const short8_t*)(ctx + (size_t)(mb + 16 * m + n) * DM + kk + g * 8);
    short8_t bfr[4];
#pragma unroll
    for (int nf = 0; nf < 4; ++nf) {
      const float* wp = wo + (size_t)(nb + 16 * nf + n) * DM + kk + g * 8;
      float4_t w0 = *(const float4_t*)wp;
      float4_t w1 = *(const float4_t*)(wp + 4);
      short8_t v;
#pragma unroll
      for (int j = 0; j < 4; ++j) { v[j] = (short)f2bf(w0[j]); v[4 + j] = (short)f2bf(w1[j]); }
      bfr[nf] = v;
    }
#pragma unroll
    for (int m = 0; m < 2; ++m)
#pragma unroll
      for (int nf = 0; nf < 4; ++nf) acc[m][nf] = MFMA(af[m], bfr[nf], acc[m][nf]);
  }

#pragma unroll
  for (int nf = 0; nf < 4; ++nf) {
    const float bv = bo[nb + 16 * nf + n];
#pragma unroll
    for (int m = 0; m < 2; ++m)
#pragma unroll
      for (int r = 0; r < 4; ++r)
        out[(size_t)(mb + 16 * m + 4 * g + r) * DM + nb + 16 * nf + n] = acc[m][nf][r] + bv;
  }
}

extern "C" void kernel_launch(void* const* d_in, const int* in_sizes, int n_in,
                              void* d_out, int out_size, void* d_ws, size_t ws_size,
                              hipStream_t stream) {
  (void)in_sizes; (void)n_in; (void)out_size; (void)ws_size;
  const float* q    = (const float*)d_in[0];
  const float* k    = (const float*)d_in[1];
  const float* v    = (const float*)d_in[2];
  const float* mask = (const float*)d_in[3];
  const float* wo   = (const float*)d_in[4];
  const float* bo   = (const float*)d_in[5];
  float* out = (float*)d_out;

  // workspace: kbf 8MB | vtr 8MB | ctx 8MB  (24MB total)
  unsigned short* kbf = (unsigned short*)d_ws;
  unsigned short* vtr = kbf + (size_t)B_ * S_ * H_ * D_;
  unsigned short* ctx = vtr + (size_t)B_ * S_ * H_ * D_;

  prep_kernel<<<3072, 256, 0, stream>>>(k, v, kbf, vtr);
  attn_kernel<<<dim3(16, 16), 512, 0, stream>>>(q, mask, kbf, vtr, ctx);
  proj_kernel<<<dim3(32, 16), 256, 0, stream>>>(ctx, wo, bo, out);
}